// Round 5
// baseline (3061.084 us; speedup 1.0000x reference)
//
#include <hip/hip_runtime.h>
#include <cstdint>

#define TT 512
#define BB 128
#define DD 512
#define HH 512
#define KTOT 1024

typedef short bf16x8 __attribute__((ext_vector_type(8)));
typedef float f32x4 __attribute__((ext_vector_type(4)));
typedef unsigned long long u64t;

__device__ inline unsigned short f2bfs(float f) {
    unsigned int u = __builtin_bit_cast(unsigned int, f);
    u = (u + 0x7FFFu + ((u >> 16) & 1u)) >> 16;
    return (unsigned short)u;
}

__device__ inline float sigf(float x) { return 1.f / (1.f + __expf(-x)); }
__device__ inline float tanhfast(float x) { return 2.f * sigf(2.f * x) - 1.f; }

__device__ inline bf16x8 load8w(const float* p) {
    const float4* p4 = (const float4*)p;
    float4 a = p4[0], b = p4[1];
    bf16x8 r;
    r[0] = (short)f2bfs(a.x); r[1] = (short)f2bfs(a.y);
    r[2] = (short)f2bfs(a.z); r[3] = (short)f2bfs(a.w);
    r[4] = (short)f2bfs(b.x); r[5] = (short)f2bfs(b.y);
    r[6] = (short)f2bfs(b.z); r[7] = (short)f2bfs(b.w);
    return r;
}

// r5: tagged self-validating h exchange in the r4 symmetric-wave structure.
//  - hbuf element = u32: (tag16 << 16) | bf16(h), tag = t+1 (1..512, never 0).
//    Data+readiness are indivisible per aligned u32 -> NO store drain, NO
//    flags, NO separate detect round-trip. One coherence hop per step.
//  - each wave polls only its OWN disjoint 32-element slice (16 u64 loads,
//    pre-issued in the previous step's shadow), re-issuing only pending
//    words. Detection == data arrival; fragments feed MFMAs from registers.
//  - slot reuse (ping-pong) is safe: a WG's step-t+2 store is ordered after
//    ALL WGs' h_t reads via [h_t loads -> data-dep -> tagged h_{t+1} store ->
//    tag validation by every peer wave (4 waves cover all 512 cols) ->
//    barrier -> data-dep -> h_{t+2} store].
//  - hbuf MUST be zeroed per launch: tags repeat 1..512 across runs, and
//    stale tag 511 in slot 0 would false-match step 511 of the next run.
__global__ __launch_bounds__(256, 1) void qlstm_kernel(
    const float* __restrict__ X,
    const float* __restrict__ Wf, const float* __restrict__ bfb,
    const float* __restrict__ Wi, const float* __restrict__ bi,
    const float* __restrict__ Wu, const float* __restrict__ bu,
    const float* __restrict__ Wo, const float* __restrict__ bo,
    const float* __restrict__ Ws1, const float* __restrict__ bs1,
    const float* __restrict__ Ws2, const float* __restrict__ bs2,
    float* __restrict__ out,
    unsigned int* __restrict__ hbuf)   // [2][BB][HH] tagged u32 ping-pong
{
    const int tid  = threadIdx.x;
    const int bid  = blockIdx.x;
    // XCD-local pipelines (speed heuristic; correctness is per-access agent-scope).
    const int rg   = bid & 7;
    const int cg   = bid >> 3;
    const int b0   = rg * 16;
    const int lane = tid & 63;
    const int wv   = tid >> 6;    // wave -> K-slice owner (all 4 gates)
    const int qd   = lane >> 4;
    const int nn   = lane & 15;

    __shared__ float pcp[4][4][16][17];   // [wave][gate][m][n] K-partials, padded

    // ---- one-time: this wave's B-fragments: 4 gates x 8 kk (x:0..3, h:4..7) ----
    bf16x8 wfr[4][8];
    {
        bf16x8 z8;
        #pragma unroll
        for (int j = 0; j < 8; ++j) z8[j] = 0;
        #pragma unroll
        for (int g = 0; g < 4; ++g) {
            const float* Wg = (g == 0) ? Wi : (g == 1) ? Wu : (g == 2) ? Wo : Wf;
            const size_t row = (g == 3) ? (size_t)nn : (size_t)(cg * 16 + nn);
            const bool valid = (g < 3) || (nn < 2);
            #pragma unroll
            for (int j = 0; j < 8; ++j) {
                const int kk = (j < 4) ? (wv * 4 + j) : (16 + wv * 4 + (j - 4));
                wfr[g][j] = valid ? load8w(Wg + row * KTOT + kk * 32 + qd * 8) : z8;
            }
        }
    }

    // ---- one-time: small params (f-head computed redundantly per-thread) ----
    const int fm = tid >> 4, fn = tid & 15;
    const int gcol = cg * 16 + fn;
    const float bir = bi[gcol], bur = bu[gcol], bor = bo[gcol];
    const float bfr0 = bfb[0], bfr1 = bfb[1];
    float ws1r[8], bs1r[4], ws2r[8];
    #pragma unroll
    for (int j = 0; j < 8; ++j) ws1r[j] = Ws1[j];
    #pragma unroll
    for (int j = 0; j < 4; ++j) bs1r[j] = bs1[j];
    #pragma unroll
    for (int j = 0; j < 8; ++j) ws2r[j] = Ws2[j];
    const float bs2r0 = bs2[0], bs2r1 = bs2[1];

    // ---- prologue "shadow": x-partials for step 0 (held in registers) ----
    f32x4 ac[4];
    #pragma unroll
    for (int g = 0; g < 4; ++g) ac[g] = f32x4{0.f, 0.f, 0.f, 0.f};
    {
        bf16x8 xa[4];
        #pragma unroll
        for (int j = 0; j < 4; ++j)
            xa[j] = load8w(X + (size_t)(b0 + nn) * DD + (wv * 4 + j) * 32 + qd * 8);
        #pragma unroll
        for (int j = 0; j < 4; ++j)
            #pragma unroll
            for (int g = 0; g < 4; ++g)
                ac[g] = __builtin_amdgcn_mfma_f32_16x16x32_bf16(xa[j], wfr[g][j], ac[g], 0, 0, 0);
    }

    float cval = 0.f;          // persistent cell state for (fm, fn)
    u64t  hw[16];              // in-flight tagged h words (2 per u64)
    unsigned int pend = 0;     // bitmask of hw[] not yet validated

    for (int t = 0; t < TT; ++t) {
        // ---- h-part: validate pre-issued tagged words, re-poll pending ----
        if (t > 0) {
            const u64t pat = ((u64t)(unsigned int)t << 16)
                           | ((u64t)(unsigned int)t << 48);
            const unsigned int* hb = hbuf + (size_t)((t - 1) & 1) * BB * HH;
            for (;;) {
                unsigned int np = 0;
                #pragma unroll
                for (int i = 0; i < 16; ++i)
                    if ((pend >> i) & 1)
                        if ((hw[i] & 0xFFFF0000FFFF0000ull) != pat) np |= 1u << i;
                pend = np;
                if (__ballot(np != 0u) == 0ull) break;
                __builtin_amdgcn_s_sleep(1);
                #pragma unroll
                for (int j = 0; j < 4; ++j) {
                    const u64t* bp = (const u64t*)(hb + (size_t)(b0 + nn) * HH
                                                   + (wv * 4 + j) * 32 + qd * 8);
                    #pragma unroll
                    for (int k = 0; k < 4; ++k)
                        if ((np >> (j * 4 + k)) & 1)
                            hw[j * 4 + k] = __hip_atomic_load(bp + k,
                                __ATOMIC_RELAXED, __HIP_MEMORY_SCOPE_AGENT);
                }
            }
            // extract bf16 fragments and fold into the gate partials
            #pragma unroll
            for (int j = 0; j < 4; ++j) {
                bf16x8 ha;
                #pragma unroll
                for (int e = 0; e < 8; ++e) {
                    const u64t w = hw[j * 4 + (e >> 1)];
                    ha[e] = (short)((e & 1) ? (unsigned int)(w >> 32)
                                            : (unsigned int)w);
                }
                #pragma unroll
                for (int g = 0; g < 4; ++g)
                    ac[g] = __builtin_amdgcn_mfma_f32_16x16x32_bf16(ha, wfr[g][4 + j], ac[g], 0, 0, 0);
            }
        }

        // ---- publish this wave's K-partials; single rendezvous ----
        #pragma unroll
        for (int g = 0; g < 4; ++g)
            #pragma unroll
            for (int r = 0; r < 4; ++r)
                pcp[wv][g][qd * 4 + r][nn] = ac[g][r];
        __syncthreads();   // (b) pcp complete

        // ---- epilogue: sum 4 partials, f-head MLP+softmax, gate update ----
        float s0g = 0.f, s1g = 0.f, s2g = 0.f, sl0 = 0.f, sl1 = 0.f;
        #pragma unroll
        for (int w = 0; w < 4; ++w) {
            s0g += pcp[w][0][fm][fn];
            s1g += pcp[w][1][fm][fn];
            s2g += pcp[w][2][fm][fn];
            sl0 += pcp[w][3][fm][0];
            sl1 += pcp[w][3][fm][1];
        }
        const float l0 = bfr0 + sl0;
        const float l1 = bfr1 + sl1;
        const float hd0 = tanhfast(ws1r[0] * l0 + ws1r[1] * l1 + bs1r[0]);
        const float hd1 = tanhfast(ws1r[2] * l0 + ws1r[3] * l1 + bs1r[1]);
        const float hd2 = tanhfast(ws1r[4] * l0 + ws1r[5] * l1 + bs1r[2]);
        const float hd3 = tanhfast(ws1r[6] * l0 + ws1r[7] * l1 + bs1r[3]);
        const float s0 = bs2r0 + ws2r[0]*hd0 + ws2r[1]*hd1 + ws2r[2]*hd2 + ws2r[3]*hd3;
        const float s1 = bs2r1 + ws2r[4]*hd0 + ws2r[5]*hd1 + ws2r[6]*hd2 + ws2r[7]*hd3;
        const float fval = sigf(s0 - s1);

        const float iv = sigf(bir + s0g);
        const float gv = tanhfast(bur + s1g);
        const float ov = sigf(bor + s2g);
        cval = fval * cval + iv * gv;
        const float hv = ov * tanhfast(cval);
        const int b = b0 + fm;

        // ---- tagged paired h store: data+readiness in one hop, no drain ----
        {
            unsigned int myw = ((unsigned int)(t + 1) << 16)
                             | (unsigned int)f2bfs(hv);
            unsigned int nbw = __shfl_xor(myw, 1);
            if ((fn & 1) == 0) {
                u64t pw = (u64t)myw | ((u64t)nbw << 32);
                __hip_atomic_store(
                    (u64t*)(hbuf + (size_t)(t & 1) * BB * HH + (size_t)b * HH + gcol),
                    pw, __ATOMIC_RELAXED, __HIP_MEMORY_SCOPE_AGENT);
            }
        }

        // ---- shadow: out stores + x-partials for t+1 + h-sweep pre-issue ----
        out[((size_t)t * BB + b) * HH + gcol] = hv;
        if (t == TT - 1) {
            out[(size_t)TT * BB * HH + (size_t)b * HH + gcol] = hv;
            out[(size_t)TT * BB * HH + (size_t)BB * HH + (size_t)b * HH + gcol] = cval;
        }
        if (t + 1 < TT) {
            #pragma unroll
            for (int g = 0; g < 4; ++g) ac[g] = f32x4{0.f, 0.f, 0.f, 0.f};
            bf16x8 xa[4];
            #pragma unroll
            for (int j = 0; j < 4; ++j)
                xa[j] = load8w(X + ((size_t)(t + 1) * BB + b0 + nn) * DD
                               + (wv * 4 + j) * 32 + qd * 8);
            #pragma unroll
            for (int j = 0; j < 4; ++j)
                #pragma unroll
                for (int g = 0; g < 4; ++g)
                    ac[g] = __builtin_amdgcn_mfma_f32_16x16x32_bf16(xa[j], wfr[g][j], ac[g], 0, 0, 0);
            // pre-issue next step's tagged h sweep (slot t&1, want tag t+1)
            const unsigned int* hb = hbuf + (size_t)(t & 1) * BB * HH;
            #pragma unroll
            for (int j = 0; j < 4; ++j) {
                const u64t* bp = (const u64t*)(hb + (size_t)(b0 + nn) * HH
                                               + (wv * 4 + j) * 32 + qd * 8);
                #pragma unroll
                for (int k = 0; k < 4; ++k)
                    hw[j * 4 + k] = __hip_atomic_load(bp + k,
                        __ATOMIC_RELAXED, __HIP_MEMORY_SCOPE_AGENT);
            }
            pend = 0xFFFFu;
        }
    }
}

extern "C" void kernel_launch(void* const* d_in, const int* in_sizes, int n_in,
                              void* d_out, int out_size, void* d_ws, size_t ws_size,
                              hipStream_t stream) {
    const float* X   = (const float*)d_in[0];
    const float* Wf  = (const float*)d_in[1];
    const float* bfb = (const float*)d_in[2];
    const float* Wi  = (const float*)d_in[3];
    const float* bi  = (const float*)d_in[4];
    const float* Wu  = (const float*)d_in[5];
    const float* bu  = (const float*)d_in[6];
    const float* Wo  = (const float*)d_in[7];
    const float* bo  = (const float*)d_in[8];
    const float* Ws1 = (const float*)d_in[9];
    const float* bs1 = (const float*)d_in[10];
    const float* Ws2 = (const float*)d_in[11];
    const float* bs2 = (const float*)d_in[12];
    float* out = (float*)d_out;

    // hbuf: [2][BB][HH] tagged u32 = 512 KB. Zeroing REQUIRED each launch:
    // tags repeat 1..512 across runs (false-match hazard at t=511).
    unsigned int* hbuf = (unsigned int*)d_ws;
    hipMemsetAsync(d_ws, 0, (size_t)2 * BB * HH * sizeof(unsigned int), stream);
    qlstm_kernel<<<dim3(256), dim3(256), 0, stream>>>(
        X, Wf, bfb, Wi, bi, Wu, bu, Wo, bo, Ws1, bs1, Ws2, bs2, out, hbuf);
}